// Round 8
// baseline (660.233 us; speedup 1.0000x reference)
//
#include <hip/hip_runtime.h>
#include <hip/hip_fp16.h>

#define N_NODES 100000
#define N_EDGES 3200000
#define OUT_DIM 176
#define LN_EPS 1e-5f

// Bucket sort parameters: bucket = row >> 9 (512 rows/bucket)
#define NBUCK 196                 // ceil(100000/512)
#define PC_BLOCKS 512
#define PC_CHUNK (N_EDGES / PC_BLOCKS)  // 6250
#define BP_CHUNK 4096
#define BP_BLOCKS ((N_EDGES + BP_CHUNK - 1) / BP_CHUNK)  // 782

// ---------------------------------------------------------------------------
// out[:, 0:64] = emb (fp32) AND emb_h = fp16(emb).
__global__ __launch_bounds__(256) void convert_emb_kernel(
    const float* __restrict__ emb, float* __restrict__ out,
    __half* __restrict__ emb_h) {
  int t = blockIdx.x * blockDim.x + threadIdx.x;
  if (t < N_NODES * 16) {
    int n = t >> 4, q = t & 15;
    float4 v = ((const float4*)emb)[t];
    ((float4*)out)[n * 44 + q] = v;
    __half2 a = __floats2half2_rn(v.x, v.y);
    __half2 b = __floats2half2_rn(v.z, v.w);
    uint2 u;
    u.x = *(unsigned int*)&a;
    u.y = *(unsigned int*)&b;
    ((uint2*)emb_h)[t] = u;
  }
}

// ---------------------------------------------------------------------------
// Pass A: per-bucket edge counts (LDS histogram per block, one global
// atomicAdd per (block,bucket)).
__global__ __launch_bounds__(256) void precount_kernel(
    const int* __restrict__ rows, int* __restrict__ gcount) {
  __shared__ int hist[NBUCK];
  for (int i = threadIdx.x; i < NBUCK; i += 256) hist[i] = 0;
  __syncthreads();
  const int e0 = blockIdx.x * PC_CHUNK;
  for (int e = e0 + threadIdx.x; e < e0 + PC_CHUNK; e += 256) {
    const int r = __builtin_nontemporal_load(rows + e);
    atomicAdd(&hist[r >> 9], 1);
  }
  __syncthreads();
  for (int i = threadIdx.x; i < NBUCK; i += 256)
    if (hist[i]) atomicAdd(&gcount[i], hist[i]);
}

// Exclusive scan of the 196 bucket counts -> bucket_base[197], cursor copy.
__global__ __launch_bounds__(256) void bucket_scan_kernel(
    const int* __restrict__ gcount, int* __restrict__ bucket_base,
    int* __restrict__ bucket_cursor) {
  __shared__ int sA[256], sB[256];
  const int t = threadIdx.x;
  int v = (t < NBUCK) ? gcount[t] : 0;
  sA[t] = v;
  __syncthreads();
  int* src = sA;
  int* dst = sB;
  for (int off = 1; off < 256; off <<= 1) {
    dst[t] = src[t] + ((t >= off) ? src[t - off] : 0);
    __syncthreads();
    int* tmp = src; src = dst; dst = tmp;
  }
  if (t < NBUCK) {
    const int excl = src[t] - v;
    bucket_base[t] = excl;
    bucket_cursor[t] = excl;
  }
  if (t == 0) bucket_base[NBUCK] = N_EDGES;
}

// ---------------------------------------------------------------------------
// Pass B: bucket the edges. Each block takes a 4096-edge chunk, LDS-counts
// per bucket, reserves one contiguous global segment per bucket (single
// atomicAdd), then writes its edges into those segments. All writes to a
// segment come from ONE block close in time -> lines written back once
// (round-6 lesson: cross-XCD interleaved 8B stores caused 6x write amp).
// meta = col | (rlow << 17):  col < 2^17, rlow = row & 511 < 2^9.
__global__ __launch_bounds__(256) void bucket_pass_kernel(
    const int* __restrict__ rows, const int* __restrict__ cols,
    const float* __restrict__ vals, int* __restrict__ bucket_cursor,
    int2* __restrict__ bucketed) {
  __shared__ int cnt[NBUCK], cur[NBUCK], gbase[NBUCK];
  for (int i = threadIdx.x; i < NBUCK; i += 256) {
    cnt[i] = 0;
    cur[i] = 0;
  }
  __syncthreads();

  const int e0 = blockIdx.x * BP_CHUNK;
  int r_[16], c_[16];
  float v_[16];
#pragma unroll
  for (int k = 0; k < 16; ++k) {
    const int e = e0 + threadIdx.x + k * 256;
    if (e < N_EDGES) {
      r_[k] = rows[e];
      c_[k] = cols[e];
      v_[k] = vals[e];
      atomicAdd(&cnt[r_[k] >> 9], 1);
    } else {
      r_[k] = -1;
    }
  }
  __syncthreads();

  for (int i = threadIdx.x; i < NBUCK; i += 256)
    gbase[i] = cnt[i] ? atomicAdd(&bucket_cursor[i], cnt[i]) : 0;
  __syncthreads();

#pragma unroll
  for (int k = 0; k < 16; ++k) {
    if (r_[k] >= 0) {
      const int b = r_[k] >> 9;
      const int lp = atomicAdd(&cur[b], 1);
      const int meta = c_[k] | ((r_[k] & 511) << 17);
      bucketed[gbase[b] + lp] = make_int2(meta, __float_as_int(v_[k]));
    }
  }
}

// ---------------------------------------------------------------------------
// Pass C: one block per bucket. LDS 512-row histogram + block scan produce
// row_ptr directly; LDS cursors scatter the bucket's edges into exact CSR
// order inside the bucket's contiguous window (single-block-owned -> no
// write bouncing, no global atomics).
__global__ __launch_bounds__(512) void csr_build_kernel(
    const int2* __restrict__ bucketed, const int* __restrict__ bucket_base,
    int* __restrict__ row_ptr, int2* __restrict__ packed) {
  __shared__ int hist[512], cur[512], sA[512], sB[512];
  const int t = threadIdx.x;
  const int blk = blockIdx.x;
  const int base = bucket_base[blk];
  const int n = bucket_base[blk + 1] - base;

  hist[t] = 0;
  __syncthreads();
  for (int i = t; i < n; i += 512) {
    const int rlow = bucketed[base + i].x >> 17;
    atomicAdd(&hist[rlow], 1);
  }
  __syncthreads();

  // inclusive scan of hist -> exclusive prefix
  sA[t] = hist[t];
  __syncthreads();
  int* src = sA;
  int* dst = sB;
  for (int off = 1; off < 512; off <<= 1) {
    dst[t] = src[t] + ((t >= off) ? src[t - off] : 0);
    __syncthreads();
    int* tmp = src; src = dst; dst = tmp;
  }
  const int excl = src[t] - hist[t];

  const int row0 = blk << 9;
  if (row0 + t < N_NODES) row_ptr[row0 + t] = base + excl;
  if (blk == NBUCK - 1 && t == 0) row_ptr[N_NODES] = N_EDGES;
  cur[t] = excl;
  __syncthreads();

  for (int i = t; i < n; i += 512) {
    const int2 m = bucketed[base + i];
    const int rlow = m.x >> 17;
    const int col = m.x & 0x1FFFF;
    const int p = atomicAdd(&cur[rlow], 1);
    packed[base + p] = make_int2(col, m.y);
  }
}

// ---------------------------------------------------------------------------
// Gather SpMM, fp16 ego table — NO LDS. One wave per node.
template <int DIN>
__global__ __launch_bounds__(512) void spmm_kernel(
    const __half* __restrict__ ego_h, const int* __restrict__ row_ptr,
    const long long* __restrict__ packed, float* __restrict__ side_out) {
  constexpr int LPH = DIN / 8;    // lanes per edge-row (16B fp16 chunks)
  constexpr int NGRP = 64 / LPH;  // edges concurrent

  const int lane = threadIdx.x & 63;
  const int li = lane % LPH;
  const int grp = lane / LPH;
  const int node = (blockIdx.x * blockDim.x + threadIdx.x) >> 6;
  if (node >= N_NODES) return;

  const uint4* __restrict__ ego8 = (const uint4*)ego_h;
  const int start = row_ptr[node];
  const int end = row_ptr[node + 1];

  float s[8] = {0.f, 0.f, 0.f, 0.f, 0.f, 0.f, 0.f, 0.f};

  for (int base = start; base < end; base += 64) {
    const int idx = base + lane;
    long long m = 0;  // col=0, val=0 padding contributes 0
    if (idx < end) m = __builtin_nontemporal_load(packed + idx);
    int mc = (int)m;
    int mv = (int)(m >> 32);
    const int cnt = min(end - base, 64);
    const int kmax = (cnt + NGRP - 1) / NGRP;
    for (int k = 0; k < kmax; ++k) {
      const int src = k * NGRP + grp;
      const int c = __shfl(mc, src, 64);
      const float v = __int_as_float(__shfl(mv, src, 64));
      uint4 raw = ego8[(long)c * LPH + li];
      const __half2* hp = (const __half2*)&raw;
      const float2 f0 = __half22float2(hp[0]);
      const float2 f1 = __half22float2(hp[1]);
      const float2 f2 = __half22float2(hp[2]);
      const float2 f3 = __half22float2(hp[3]);
      s[0] += v * f0.x; s[1] += v * f0.y;
      s[2] += v * f1.x; s[3] += v * f1.y;
      s[4] += v * f2.x; s[5] += v * f2.y;
      s[6] += v * f3.x; s[7] += v * f3.y;
    }
  }

#pragma unroll
  for (int mask = LPH; mask < 64; mask <<= 1) {
#pragma unroll
    for (int r = 0; r < 8; ++r) s[r] += __shfl_xor(s[r], mask, 64);
  }

  if (grp == 0) {
    float4 st0 = make_float4(s[0], s[1], s[2], s[3]);
    float4 st1 = make_float4(s[4], s[5], s[6], s[7]);
    ((float4*)side_out)[(long)node * (DIN / 4) + 2 * li + 0] = st0;
    ((float4*)side_out)[(long)node * (DIN / 4) + 2 * li + 1] = st1;
  }
}

// ---------------------------------------------------------------------------
// Dense + LN + l2norm, zero LDS; weight columns in VGPRs, grid-stride.
// Grid must EXCEED the VGPR-capped occupancy (round-7 lesson: 512 blocks =
// 8 waves/CU grid-cap, measured 20% occ / 49% VALU; VGPR=124 allows 16/CU).
template <int DIN, int DOUT, int COL_OFF>
__global__ __launch_bounds__(256) void dense_kernel(
    const __half* __restrict__ ego_h, const float* __restrict__ side,
    const float* __restrict__ w1, const float* __restrict__ b1,
    const float* __restrict__ w2, const float* __restrict__ b2,
    const float* __restrict__ g1, const float* __restrict__ be1,
    const float* __restrict__ g2, const float* __restrict__ be2,
    __half* __restrict__ ego_h_out, float* __restrict__ out) {
  constexpr int NPW = 64 / DOUT;
  constexpr int Q8 = DIN / 8;

  const int lane = threadIdx.x & 63;
  const int j = lane % DOUT;
  const int sub = lane / DOUT;

  float wr1[DIN], wr2[DIN];
#pragma unroll
  for (int i = 0; i < DIN; ++i) {
    wr1[i] = w1[i * DOUT + j];
    wr2[i] = w2[i * DOUT + j];
  }
  const float bb1 = b1[j], bb2 = b2[j];
  const float gg1 = g1[j], gg2 = g2[j];
  const float bbe1 = be1[j], bbe2 = be2[j];

  const uint4* __restrict__ ego8 = (const uint4*)ego_h;
  const float4* __restrict__ side4 = (const float4*)side;

  const int waveId = (blockIdx.x * blockDim.x + threadIdx.x) >> 6;
  const int nwaves = (gridDim.x * blockDim.x) >> 6;
  const int ngroups = N_NODES / NPW;

  for (int gidx = waveId; gidx < ngroups; gidx += nwaves) {
    const int node = gidx * NPW + sub;

    float acc1 = bb1, acc2 = bb2;
#pragma unroll
    for (int q = 0; q < Q8; ++q) {
      uint4 raw = ego8[(long)node * Q8 + q];
      const __half2* hp = (const __half2*)&raw;
      const float2 e0 = __half22float2(hp[0]);
      const float2 e1 = __half22float2(hp[1]);
      const float2 e2 = __half22float2(hp[2]);
      const float2 e3 = __half22float2(hp[3]);
      const float4 sa = side4[(long)node * (DIN / 4) + 2 * q + 0];
      const float4 sb = side4[(long)node * (DIN / 4) + 2 * q + 1];
      const float ee[8] = {e0.x, e0.y, e1.x, e1.y, e2.x, e2.y, e3.x, e3.y};
      const float ssv[8] = {sa.x, sa.y, sa.z, sa.w, sb.x, sb.y, sb.z, sb.w};
#pragma unroll
      for (int r = 0; r < 8; ++r) {
        const float xs = ee[r] + ssv[r];
        const float xp = ee[r] * ssv[r];
        acc1 += xs * wr1[8 * q + r];
        acc2 += xp * wr2[8 * q + r];
      }
    }

    float h1 = acc1 > 0.f ? acc1 : 0.01f * acc1;
    float h2 = acc2 > 0.f ? acc2 : 0.01f * acc2;

    float m1 = h1, m2 = h2;
#pragma unroll
    for (int mask = DOUT / 2; mask > 0; mask >>= 1) {
      m1 += __shfl_xor(m1, mask, DOUT);
      m2 += __shfl_xor(m2, mask, DOUT);
    }
    m1 *= (1.0f / DOUT);
    m2 *= (1.0f / DOUT);
    float d1 = h1 - m1, d2 = h2 - m2;
    float v1 = d1 * d1, v2 = d2 * d2;
#pragma unroll
    for (int mask = DOUT / 2; mask > 0; mask >>= 1) {
      v1 += __shfl_xor(v1, mask, DOUT);
      v2 += __shfl_xor(v2, mask, DOUT);
    }
    v1 *= (1.0f / DOUT);
    v2 *= (1.0f / DOUT);
    const float sv = d1 * rsqrtf(v1 + LN_EPS) * gg1 + bbe1;
    const float bv = d2 * rsqrtf(v2 + LN_EPS) * gg2 + bbe2;
    const float en = sv + bv;

    float ss = en * en;
#pragma unroll
    for (int mask = DOUT / 2; mask > 0; mask >>= 1) {
      ss += __shfl_xor(ss, mask, DOUT);
    }
    const float ov = en / fmaxf(sqrtf(ss), 1e-12f);

    if (ego_h_out) ego_h_out[(long)node * DOUT + j] = __float2half(en);
    out[(long)node * OUT_DIM + COL_OFF + j] = ov;
  }
}

// ---------------------------------------------------------------------------
extern "C" void kernel_launch(void* const* d_in, const int* in_sizes, int n_in,
                              void* d_out, int out_size, void* d_ws,
                              size_t ws_size, hipStream_t stream) {
  const float* emb = (const float*)d_in[0];
  const int* rows = (const int*)d_in[1];
  const int* cols = (const int*)d_in[2];
  const float* vals = (const float*)d_in[3];

  const float* P[3][8];
  for (int k = 0; k < 3; ++k)
    for (int p = 0; p < 8; ++p) P[k][p] = (const float*)d_in[4 + 8 * k + p];

  float* out = (float*)d_out;

  char* ws = (char*)d_ws;
  int2* packed = (int2*)ws;                              // E*8   = 25.6 MB
  float* side = (float*)(ws + (size_t)N_EDGES * 8);      // N*64*4 = 25.6 MB
  int2* bucketed = (int2*)side;  // ALIAS: dead before spmm writes side
  __half* emb_h = (__half*)(side + (size_t)N_NODES * 64);  // 12.8 MB
  __half* ego1_h = emb_h + (size_t)N_NODES * 64;           // 12.8 MB
  __half* ego2_h = ego1_h + (size_t)N_NODES * 64;          // 6.4 MB
  int* row_ptr = (int*)(ego2_h + (size_t)N_NODES * 32);  // N+1
  int* gcount = row_ptr + (N_NODES + 1);                 // 196
  int* bucket_base = gcount + NBUCK;                     // 197
  int* bucket_cursor = bucket_base + (NBUCK + 1);        // 196

  // ---- CSR build via two-level bucket sort ----
  hipMemsetAsync(gcount, 0, NBUCK * sizeof(int), stream);
  precount_kernel<<<PC_BLOCKS, 256, 0, stream>>>(rows, gcount);
  bucket_scan_kernel<<<1, 256, 0, stream>>>(gcount, bucket_base,
                                            bucket_cursor);
  bucket_pass_kernel<<<BP_BLOCKS, 256, 0, stream>>>(rows, cols, vals,
                                                    bucket_cursor, bucketed);
  csr_build_kernel<<<NBUCK, 512, 0, stream>>>(bucketed, bucket_base, row_ptr,
                                              packed);

  convert_emb_kernel<<<(N_NODES * 16 + 255) / 256, 256, 0, stream>>>(emb, out,
                                                                     emb_h);

  const int SPMM_BLOCKS = (N_NODES + 7) / 8;  // wave/node, 512 threads
  const int DENSE_BLOCKS = 4096;              // saturate VGPR-capped occ

  // ---- layer 0: 64 -> 64 ----
  spmm_kernel<64><<<SPMM_BLOCKS, 512, 0, stream>>>(
      emb_h, row_ptr, (const long long*)packed, side);
  dense_kernel<64, 64, 64><<<DENSE_BLOCKS, 256, 0, stream>>>(
      emb_h, side, P[0][0], P[0][1], P[0][2], P[0][3], P[0][4], P[0][5],
      P[0][6], P[0][7], ego1_h, out);

  // ---- layer 1: 64 -> 32 ----
  spmm_kernel<64><<<SPMM_BLOCKS, 512, 0, stream>>>(
      ego1_h, row_ptr, (const long long*)packed, side);
  dense_kernel<64, 32, 128><<<DENSE_BLOCKS, 256, 0, stream>>>(
      ego1_h, side, P[1][0], P[1][1], P[1][2], P[1][3], P[1][4], P[1][5],
      P[1][6], P[1][7], ego2_h, out);

  // ---- layer 2: 32 -> 16 ----
  spmm_kernel<32><<<SPMM_BLOCKS, 512, 0, stream>>>(
      ego2_h, row_ptr, (const long long*)packed, side);
  dense_kernel<32, 16, 160><<<DENSE_BLOCKS, 256, 0, stream>>>(
      ego2_h, side, P[2][0], P[2][1], P[2][2], P[2][3], P[2][4], P[2][5],
      P[2][6], P[2][7], nullptr, out);
}

// Round 9
// 633.477 us; speedup vs baseline: 1.0422x; 1.0422x over previous
//
#include <hip/hip_runtime.h>
#include <hip/hip_fp16.h>

#define N_NODES 100000
#define N_EDGES 3200000
#define OUT_DIM 176
#define LN_EPS 1e-5f

typedef _Float16 h2 __attribute__((ext_vector_type(2)));

// Bucket sort parameters: bucket = row >> 9 (512 rows/bucket)
#define NBUCK 196
#define PC_BLOCKS 512
#define PC_CHUNK (N_EDGES / PC_BLOCKS)  // 6250
#define BP_CHUNK 4096
#define BP_BLOCKS ((N_EDGES + BP_CHUNK - 1) / BP_CHUNK)  // 782

// ---------------------------------------------------------------------------
// out[:, 0:64] = emb (fp32) AND emb_h = fp16(emb).
__global__ __launch_bounds__(256) void convert_emb_kernel(
    const float* __restrict__ emb, float* __restrict__ out,
    __half* __restrict__ emb_h) {
  int t = blockIdx.x * blockDim.x + threadIdx.x;
  if (t < N_NODES * 16) {
    int n = t >> 4, q = t & 15;
    float4 v = ((const float4*)emb)[t];
    ((float4*)out)[n * 44 + q] = v;
    __half2 a = __floats2half2_rn(v.x, v.y);
    __half2 b = __floats2half2_rn(v.z, v.w);
    uint2 u;
    u.x = *(unsigned int*)&a;
    u.y = *(unsigned int*)&b;
    ((uint2*)emb_h)[t] = u;
  }
}

// ---------------------------------------------------------------------------
// Weight prep: wt[j*DIN+i] = (half)w[i*DOUT+j]  (transposed, fp16).
// Round-8 lesson: per-wave preload of column-major fp32 weights fans 64
// cache lines per instruction; transposed-fp16 makes it 8 coalesced uint4s.
__global__ __launch_bounds__(256) void wprep_kernel(
    const float* __restrict__ w1, const float* __restrict__ w2,
    __half* __restrict__ wt1, __half* __restrict__ wt2, int din, int dout) {
  int idx = blockIdx.x * 256 + threadIdx.x;
  if (idx < din * dout) {
    int i = idx / dout, j = idx % dout;
    wt1[j * din + i] = __float2half(w1[idx]);
    wt2[j * din + i] = __float2half(w2[idx]);
  }
}

// ---------------------------------------------------------------------------
// Pass A: per-bucket edge counts.
__global__ __launch_bounds__(256) void precount_kernel(
    const int* __restrict__ rows, int* __restrict__ gcount) {
  __shared__ int hist[NBUCK];
  for (int i = threadIdx.x; i < NBUCK; i += 256) hist[i] = 0;
  __syncthreads();
  const int e0 = blockIdx.x * PC_CHUNK;
  for (int e = e0 + threadIdx.x; e < e0 + PC_CHUNK; e += 256) {
    const int r = __builtin_nontemporal_load(rows + e);
    atomicAdd(&hist[r >> 9], 1);
  }
  __syncthreads();
  for (int i = threadIdx.x; i < NBUCK; i += 256)
    if (hist[i]) atomicAdd(&gcount[i], hist[i]);
}

// Exclusive scan of bucket counts -> bucket_base[197], cursor copy.
__global__ __launch_bounds__(256) void bucket_scan_kernel(
    const int* __restrict__ gcount, int* __restrict__ bucket_base,
    int* __restrict__ bucket_cursor) {
  __shared__ int sA[256], sB[256];
  const int t = threadIdx.x;
  int v = (t < NBUCK) ? gcount[t] : 0;
  sA[t] = v;
  __syncthreads();
  int* src = sA;
  int* dst = sB;
  for (int off = 1; off < 256; off <<= 1) {
    dst[t] = src[t] + ((t >= off) ? src[t - off] : 0);
    __syncthreads();
    int* tmp = src; src = dst; dst = tmp;
  }
  if (t < NBUCK) {
    const int excl = src[t] - v;
    bucket_base[t] = excl;
    bucket_cursor[t] = excl;
  }
  if (t == 0) bucket_base[NBUCK] = N_EDGES;
}

// ---------------------------------------------------------------------------
// Pass B: bucket the edges (single-block-owned contiguous segments; lines
// written back once — round-6 lesson).
__global__ __launch_bounds__(256) void bucket_pass_kernel(
    const int* __restrict__ rows, const int* __restrict__ cols,
    const float* __restrict__ vals, int* __restrict__ bucket_cursor,
    int2* __restrict__ bucketed) {
  __shared__ int cnt[NBUCK], cur[NBUCK], gbase[NBUCK];
  for (int i = threadIdx.x; i < NBUCK; i += 256) {
    cnt[i] = 0;
    cur[i] = 0;
  }
  __syncthreads();

  const int e0 = blockIdx.x * BP_CHUNK;
  int r_[16], c_[16];
  float v_[16];
#pragma unroll
  for (int k = 0; k < 16; ++k) {
    const int e = e0 + threadIdx.x + k * 256;
    if (e < N_EDGES) {
      r_[k] = rows[e];
      c_[k] = cols[e];
      v_[k] = vals[e];
      atomicAdd(&cnt[r_[k] >> 9], 1);
    } else {
      r_[k] = -1;
    }
  }
  __syncthreads();

  for (int i = threadIdx.x; i < NBUCK; i += 256)
    gbase[i] = cnt[i] ? atomicAdd(&bucket_cursor[i], cnt[i]) : 0;
  __syncthreads();

#pragma unroll
  for (int k = 0; k < 16; ++k) {
    if (r_[k] >= 0) {
      const int b = r_[k] >> 9;
      const int lp = atomicAdd(&cur[b], 1);
      const int meta = c_[k] | ((r_[k] & 511) << 17);
      bucketed[gbase[b] + lp] = make_int2(meta, __float_as_int(v_[k]));
    }
  }
}

// ---------------------------------------------------------------------------
// Pass C: one block per bucket -> row_ptr + exact CSR order.
__global__ __launch_bounds__(512) void csr_build_kernel(
    const int2* __restrict__ bucketed, const int* __restrict__ bucket_base,
    int* __restrict__ row_ptr, int2* __restrict__ packed) {
  __shared__ int hist[512], cur[512], sA[512], sB[512];
  const int t = threadIdx.x;
  const int blk = blockIdx.x;
  const int base = bucket_base[blk];
  const int n = bucket_base[blk + 1] - base;

  hist[t] = 0;
  __syncthreads();
  for (int i = t; i < n; i += 512) {
    const int rlow = bucketed[base + i].x >> 17;
    atomicAdd(&hist[rlow], 1);
  }
  __syncthreads();

  sA[t] = hist[t];
  __syncthreads();
  int* src = sA;
  int* dst = sB;
  for (int off = 1; off < 512; off <<= 1) {
    dst[t] = src[t] + ((t >= off) ? src[t - off] : 0);
    __syncthreads();
    int* tmp = src; src = dst; dst = tmp;
  }
  const int excl = src[t] - hist[t];

  const int row0 = blk << 9;
  if (row0 + t < N_NODES) row_ptr[row0 + t] = base + excl;
  if (blk == NBUCK - 1 && t == 0) row_ptr[N_NODES] = N_EDGES;
  cur[t] = excl;
  __syncthreads();

  for (int i = t; i < n; i += 512) {
    const int2 m = bucketed[base + i];
    const int rlow = m.x >> 17;
    const int col = m.x & 0x1FFFF;
    const int p = atomicAdd(&cur[rlow], 1);
    packed[base + p] = make_int2(col, m.y);
  }
}

// ---------------------------------------------------------------------------
// Gather SpMM, fp16 ego table — NO LDS. One wave per node.
// Epilogue now writes side as fp16 (dense consumes it via v_dot2).
template <int DIN>
__global__ __launch_bounds__(512) void spmm_kernel(
    const __half* __restrict__ ego_h, const int* __restrict__ row_ptr,
    const long long* __restrict__ packed, __half* __restrict__ side_out_h) {
  constexpr int LPH = DIN / 8;    // lanes per edge-row (16B fp16 chunks)
  constexpr int NGRP = 64 / LPH;  // edges concurrent

  const int lane = threadIdx.x & 63;
  const int li = lane % LPH;
  const int grp = lane / LPH;
  const int node = (blockIdx.x * blockDim.x + threadIdx.x) >> 6;
  if (node >= N_NODES) return;

  const uint4* __restrict__ ego8 = (const uint4*)ego_h;
  const int start = row_ptr[node];
  const int end = row_ptr[node + 1];

  float s[8] = {0.f, 0.f, 0.f, 0.f, 0.f, 0.f, 0.f, 0.f};

  for (int base = start; base < end; base += 64) {
    const int idx = base + lane;
    long long m = 0;  // col=0, val=0 padding contributes 0
    if (idx < end) m = __builtin_nontemporal_load(packed + idx);
    int mc = (int)m;
    int mv = (int)(m >> 32);
    const int cnt = min(end - base, 64);
    const int kmax = (cnt + NGRP - 1) / NGRP;
    for (int k = 0; k < kmax; ++k) {
      const int src = k * NGRP + grp;
      const int c = __shfl(mc, src, 64);
      const float v = __int_as_float(__shfl(mv, src, 64));
      uint4 raw = ego8[(long)c * LPH + li];
      const __half2* hp = (const __half2*)&raw;
      const float2 f0 = __half22float2(hp[0]);
      const float2 f1 = __half22float2(hp[1]);
      const float2 f2 = __half22float2(hp[2]);
      const float2 f3 = __half22float2(hp[3]);
      s[0] += v * f0.x; s[1] += v * f0.y;
      s[2] += v * f1.x; s[3] += v * f1.y;
      s[4] += v * f2.x; s[5] += v * f2.y;
      s[6] += v * f3.x; s[7] += v * f3.y;
    }
  }

#pragma unroll
  for (int mask = LPH; mask < 64; mask <<= 1) {
#pragma unroll
    for (int r = 0; r < 8; ++r) s[r] += __shfl_xor(s[r], mask, 64);
  }

  if (grp == 0) {
    __half2 p0 = __floats2half2_rn(s[0], s[1]);
    __half2 p1 = __floats2half2_rn(s[2], s[3]);
    __half2 p2 = __floats2half2_rn(s[4], s[5]);
    __half2 p3 = __floats2half2_rn(s[6], s[7]);
    uint4 u;
    u.x = *(unsigned int*)&p0;
    u.y = *(unsigned int*)&p1;
    u.z = *(unsigned int*)&p2;
    u.w = *(unsigned int*)&p3;
    ((uint4*)side_out_h)[(long)node * LPH + li] = u;
  }
}

// ---------------------------------------------------------------------------
// Dense + LN + l2norm: transposed-fp16 weights in VGPRs (coalesced uint4
// preload), packed-half xs/xp + v_dot2_f32_f16 accumulation (fp32 acc).
template <int DIN, int DOUT, int COL_OFF>
__global__ __launch_bounds__(256) void dense_kernel(
    const __half* __restrict__ ego_h, const __half* __restrict__ side_h,
    const __half* __restrict__ w1t, const float* __restrict__ b1,
    const __half* __restrict__ w2t, const float* __restrict__ b2,
    const float* __restrict__ g1, const float* __restrict__ be1,
    const float* __restrict__ g2, const float* __restrict__ be2,
    __half* __restrict__ ego_h_out, float* __restrict__ out) {
  constexpr int NPW = 64 / DOUT;
  constexpr int Q8 = DIN / 8;  // uint4 (8-half) chunks per row

  const int lane = threadIdx.x & 63;
  const int j = lane % DOUT;
  const int sub = lane / DOUT;

  // coalesced transposed-weight preload: row j = Q8 uint4s
  const uint4* __restrict__ w1u = (const uint4*)w1t;
  const uint4* __restrict__ w2u = (const uint4*)w2t;
  uint4 wraw1[Q8], wraw2[Q8];
#pragma unroll
  for (int q = 0; q < Q8; ++q) {
    wraw1[q] = w1u[j * Q8 + q];
    wraw2[q] = w2u[j * Q8 + q];
  }
  const float bb1 = b1[j], bb2 = b2[j];
  const float gg1 = g1[j], gg2 = g2[j];
  const float bbe1 = be1[j], bbe2 = be2[j];

  const uint4* __restrict__ ego8 = (const uint4*)ego_h;
  const uint4* __restrict__ side8 = (const uint4*)side_h;

  const int waveId = (blockIdx.x * blockDim.x + threadIdx.x) >> 6;
  const int nwaves = (gridDim.x * blockDim.x) >> 6;
  const int ngroups = N_NODES / NPW;

  for (int gidx = waveId; gidx < ngroups; gidx += nwaves) {
    const int node = gidx * NPW + sub;

    float acc1 = bb1, acc2 = bb2;
#pragma unroll
    for (int q = 0; q < Q8; ++q) {
      uint4 eraw = ego8[(long)node * Q8 + q];
      uint4 sraw = side8[(long)node * Q8 + q];
      const h2* e2 = (const h2*)&eraw;
      const h2* s2 = (const h2*)&sraw;
      const h2* wq1 = (const h2*)&wraw1[q];
      const h2* wq2 = (const h2*)&wraw2[q];
#pragma unroll
      for (int r = 0; r < 4; ++r) {
        const h2 xs = e2[r] + s2[r];
        const h2 xp = e2[r] * s2[r];
#if __has_builtin(__builtin_amdgcn_fdot2)
        acc1 = __builtin_amdgcn_fdot2(xs, wq1[r], acc1, false);
        acc2 = __builtin_amdgcn_fdot2(xp, wq2[r], acc2, false);
#else
        acc1 += (float)xs.x * (float)wq1[r].x + (float)xs.y * (float)wq1[r].y;
        acc2 += (float)xp.x * (float)wq2[r].x + (float)xp.y * (float)wq2[r].y;
#endif
      }
    }

    float h1 = acc1 > 0.f ? acc1 : 0.01f * acc1;
    float h2v = acc2 > 0.f ? acc2 : 0.01f * acc2;

    float m1 = h1, m2 = h2v;
#pragma unroll
    for (int mask = DOUT / 2; mask > 0; mask >>= 1) {
      m1 += __shfl_xor(m1, mask, DOUT);
      m2 += __shfl_xor(m2, mask, DOUT);
    }
    m1 *= (1.0f / DOUT);
    m2 *= (1.0f / DOUT);
    float d1 = h1 - m1, d2 = h2v - m2;
    float v1 = d1 * d1, v2 = d2 * d2;
#pragma unroll
    for (int mask = DOUT / 2; mask > 0; mask >>= 1) {
      v1 += __shfl_xor(v1, mask, DOUT);
      v2 += __shfl_xor(v2, mask, DOUT);
    }
    v1 *= (1.0f / DOUT);
    v2 *= (1.0f / DOUT);
    const float sv = d1 * rsqrtf(v1 + LN_EPS) * gg1 + bbe1;
    const float bv = d2 * rsqrtf(v2 + LN_EPS) * gg2 + bbe2;
    const float en = sv + bv;

    float ss = en * en;
#pragma unroll
    for (int mask = DOUT / 2; mask > 0; mask >>= 1) {
      ss += __shfl_xor(ss, mask, DOUT);
    }
    const float ov = en / fmaxf(sqrtf(ss), 1e-12f);

    if (ego_h_out) ego_h_out[(long)node * DOUT + j] = __float2half(en);
    out[(long)node * OUT_DIM + COL_OFF + j] = ov;
  }
}

// ---------------------------------------------------------------------------
extern "C" void kernel_launch(void* const* d_in, const int* in_sizes, int n_in,
                              void* d_out, int out_size, void* d_ws,
                              size_t ws_size, hipStream_t stream) {
  const float* emb = (const float*)d_in[0];
  const int* rows = (const int*)d_in[1];
  const int* cols = (const int*)d_in[2];
  const float* vals = (const float*)d_in[3];

  const float* P[3][8];
  for (int k = 0; k < 3; ++k)
    for (int p = 0; p < 8; ++p) P[k][p] = (const float*)d_in[4 + 8 * k + p];

  float* out = (float*)d_out;

  char* ws = (char*)d_ws;
  int2* packed = (int2*)ws;                          // E*8   = 25.6 MB
  char* sideArea = ws + (size_t)N_EDGES * 8;         // 25.6 MB region
  __half* side_h = (__half*)sideArea;                // N*64*2 = 12.8 MB used
  int2* bucketed = (int2*)sideArea;  // ALIAS: dead before spmm writes side
  __half* emb_h = (__half*)(sideArea + (size_t)N_NODES * 64 * 4);  // 12.8 MB
  __half* ego1_h = emb_h + (size_t)N_NODES * 64;                   // 12.8 MB
  __half* ego2_h = ego1_h + (size_t)N_NODES * 64;                  // 6.4 MB
  // transposed fp16 weights (16B-aligned block)
  __half* wt1_0 = ego2_h + (size_t)N_NODES * 32;  // 4096 halves
  __half* wt2_0 = wt1_0 + 4096;
  __half* wt1_1 = wt2_0 + 4096;  // 2048
  __half* wt2_1 = wt1_1 + 2048;
  __half* wt1_2 = wt2_1 + 2048;  // 512
  __half* wt2_2 = wt1_2 + 512;
  int* row_ptr = (int*)(wt2_2 + 512);  // N+1
  int* gcount = row_ptr + (N_NODES + 1);
  int* bucket_base = gcount + NBUCK;
  int* bucket_cursor = bucket_base + (NBUCK + 1);

  // ---- CSR build via two-level bucket sort ----
  hipMemsetAsync(gcount, 0, NBUCK * sizeof(int), stream);
  precount_kernel<<<PC_BLOCKS, 256, 0, stream>>>(rows, gcount);
  bucket_scan_kernel<<<1, 256, 0, stream>>>(gcount, bucket_base,
                                            bucket_cursor);
  bucket_pass_kernel<<<BP_BLOCKS, 256, 0, stream>>>(rows, cols, vals,
                                                    bucket_cursor, bucketed);
  csr_build_kernel<<<NBUCK, 512, 0, stream>>>(bucketed, bucket_base, row_ptr,
                                              packed);

  // ---- weight prep (transposed fp16) ----
  wprep_kernel<<<16, 256, 0, stream>>>(P[0][0], P[0][2], wt1_0, wt2_0, 64, 64);
  wprep_kernel<<<8, 256, 0, stream>>>(P[1][0], P[1][2], wt1_1, wt2_1, 64, 32);
  wprep_kernel<<<2, 256, 0, stream>>>(P[2][0], P[2][2], wt1_2, wt2_2, 32, 16);

  convert_emb_kernel<<<(N_NODES * 16 + 255) / 256, 256, 0, stream>>>(emb, out,
                                                                     emb_h);

  const int SPMM_BLOCKS = (N_NODES + 7) / 8;  // wave/node, 512 threads
  const int DENSE_BLOCKS = 1280;              // ~5 blocks/CU co-resident

  // ---- layer 0: 64 -> 64 ----
  spmm_kernel<64><<<SPMM_BLOCKS, 512, 0, stream>>>(
      emb_h, row_ptr, (const long long*)packed, side_h);
  dense_kernel<64, 64, 64><<<DENSE_BLOCKS, 256, 0, stream>>>(
      emb_h, side_h, wt1_0, P[0][1], wt2_0, P[0][3], P[0][4], P[0][5],
      P[0][6], P[0][7], ego1_h, out);

  // ---- layer 1: 64 -> 32 ----
  spmm_kernel<64><<<SPMM_BLOCKS, 512, 0, stream>>>(
      ego1_h, row_ptr, (const long long*)packed, side_h);
  dense_kernel<64, 32, 128><<<DENSE_BLOCKS, 256, 0, stream>>>(
      ego1_h, side_h, wt1_1, P[1][1], wt2_1, P[1][3], P[1][4], P[1][5],
      P[1][6], P[1][7], ego2_h, out);

  // ---- layer 2: 32 -> 16 ----
  spmm_kernel<32><<<SPMM_BLOCKS, 512, 0, stream>>>(
      ego2_h, row_ptr, (const long long*)packed, side_h);
  dense_kernel<32, 16, 160><<<DENSE_BLOCKS, 256, 0, stream>>>(
      ego2_h, side_h, wt1_2, P[2][1], wt2_2, P[2][3], P[2][4], P[2][5],
      P[2][6], P[2][7], nullptr, out);
}